// Round 20
// baseline (85.648 us; speedup 1.0000x reference)
//
#include <hip/hip_runtime.h>
#include <cstdint>
#include <cstddef>

#define S_LEN 2048
#define BATCH 2
#define HQ    16
#define HKV   4
#define DH    128
#define KVB   64
#define PPW   64     // pbuf row stride (shorts), XOR-swizzled 8-short chunks
#define NQT   32     // 32 Q-tiles of 64 rows
// fallback (r2 kernel) params
#define QT0   64
#define KVB0  32
#define VP    40
#define PP    40

typedef float  f4     __attribute__((ext_vector_type(4)));
typedef float  f32x4  __attribute__((ext_vector_type(4)));
typedef short  short8 __attribute__((ext_vector_type(8)));
typedef __bf16 bf16x8 __attribute__((ext_vector_type(8)));

__device__ __forceinline__ unsigned short f2bf(float x) {
    unsigned u = __builtin_bit_cast(unsigned, x);
    u += 0x7fffu + ((u >> 16) & 1u);          // RNE
    return (unsigned short)(u >> 16);
}
__device__ __forceinline__ float bf2f(unsigned short s) {
    return __builtin_bit_cast(float, (unsigned)s << 16);
}
__device__ __forceinline__ void gld16(const void* g, void* l) {
    __builtin_amdgcn_global_load_lds(
        (const __attribute__((address_space(1))) unsigned int*)g,
        (__attribute__((address_space(3))) unsigned int*)l, 16, 0, 0);
}
// 16-lane max reduce+broadcast, all-VALU via DPP (no LDS pipe)
__device__ __forceinline__ float dpp_max16(float x) {
    int xi; float y;
    xi = __builtin_bit_cast(int, x);
    y = __builtin_bit_cast(float, __builtin_amdgcn_mov_dpp(xi, 0xB1, 0xF, 0xF, true));  // quad_perm xor1
    x = fmaxf(x, y);
    xi = __builtin_bit_cast(int, x);
    y = __builtin_bit_cast(float, __builtin_amdgcn_mov_dpp(xi, 0x4E, 0xF, 0xF, true));  // quad_perm xor2
    x = fmaxf(x, y);
    xi = __builtin_bit_cast(int, x);
    y = __builtin_bit_cast(float, __builtin_amdgcn_mov_dpp(xi, 0x124, 0xF, 0xF, true)); // row_ror:4
    x = fmaxf(x, y);
    xi = __builtin_bit_cast(int, x);
    y = __builtin_bit_cast(float, __builtin_amdgcn_mov_dpp(xi, 0x128, 0xF, 0xF, true)); // row_ror:8
    x = fmaxf(x, y);
    return x;
}

// ---------------- fused pre-pass: K -> bf16 swizzled rows AND V -> bf16 transposed tiles
__global__ __launch_bounds__(256)
void prep_kv(const float* __restrict__ K, const float* __restrict__ V,
             short* __restrict__ Kout, short* __restrict__ Vout) {
    __shared__ short t[64][136];
    const int blk = blockIdx.x, bh = blk >> 5, tile = blk & 31, tid = threadIdx.x;
    // ---- K: rows, 8-el chunks XOR-swizzled (no LDS)
    {
        const int r  = tid >> 2;                 // 0..63 row within tile
        const int s  = tile * 64 + r;
        const int c0 = (tid & 3) * 32;
        const float* src = K + ((size_t)s * (BATCH * HKV) + bh) * DH + c0;
        short* dst = Kout + ((size_t)bh * S_LEN + s) * DH;
        const int sw = (r & 7) << 3;
        #pragma unroll
        for (int ks = 0; ks < 4; ++ks) {
            f4 a  = ((const f4*)src)[ks * 2];
            f4 b2 = ((const f4*)src)[ks * 2 + 1];
            short8 o;
            #pragma unroll
            for (int j = 0; j < 4; ++j) { o[j] = (short)f2bf(a[j]); o[4 + j] = (short)f2bf(b2[j]); }
            *(short8*)&dst[(c0 + ks * 8) ^ sw] = o;
        }
    }
    // ---- V: load into LDS (bf16), then write transposed [d][kv], swizzled
    {
        const int r  = tid >> 2;
        const int c0 = (tid & 3) * 32;
        const float* src = V + ((size_t)(tile * 64 + r) * (BATCH * HKV) + bh) * DH + c0;
        #pragma unroll
        for (int m = 0; m < 8; ++m) {
            f4 x = ((const f4*)src)[m];
            #pragma unroll
            for (int j = 0; j < 4; ++j) t[r][c0 + m * 4 + j] = (short)f2bf(x[j]);
        }
    }
    __syncthreads();
    {
        const int d   = tid >> 1;             // 0..127
        const int cc0 = (tid & 1) * 32;
        const int sw  = (d & 7) << 3;
        short* dst = Vout + (size_t)bh * (S_LEN * DH) + (size_t)tile * (64 * DH) + d * 64 + cc0;
        #pragma unroll
        for (int c8 = 0; c8 < 4; ++c8) {
            const int base = (cc0 + c8 * 8) ^ sw;
            short8 v;
            #pragma unroll
            for (int j = 0; j < 8; ++j) v[j] = t[base + j][d];
            ((short8*)dst)[c8] = v;
        }
    }
}

// ---------------- main: 16x16-frag 4-wave blocks, SINGLE-buffered 40KB LDS,
// forced 4 blocks/CU (16 waves/CU = 4 waves/SIMD, 4 barrier domains).
// Per-wave regs ~124 (92 VGPR + 32 AGPR) fits the 128-reg cap from (256,4).
__global__ __launch_bounds__(256, 4)
void fattn_main(const float* __restrict__ Q, const short* __restrict__ Kb,
                const short* __restrict__ Vb, float* __restrict__ O)
{
    __shared__ short kbuf[KVB * DH];       // 16KB (rows XOR-swizzled)
    __shared__ short vbuf[DH * KVB];       // 16KB ([d][kv] swizzled)
    __shared__ short pbuf[4][16 * PPW];    // 8KB (per-wave 2KB)

    const int bh  = blockIdx.y;
    const int b   = bh >> 4, h = bh & 15, hkv = h >> 2;
    const int bh2 = b * HKV + hkv;
    const int px  = blockIdx.x;            // 0..15; pair (31-px, px)
    const int tid = threadIdx.x;
    const int wid = tid >> 6;              // 0..3
    const int lane = tid & 63;
    const int lr  = lane & 15;
    const int kb  = lane >> 4;

    const float QS = 0.127517244f;         // (1/sqrt(128)) * log2(e)
    short8 ones_s;
    #pragma unroll
    for (int j = 0; j < 8; ++j) ones_s[j] = (short)0x3F80;   // bf16 1.0
    const bf16x8 ones = __builtin_bit_cast(bf16x8, ones_s);

    const char* ksrc = (const char*)(Kb + (size_t)bh2 * S_LEN * DH);
    const char* vsrc = (const char*)(Vb + (size_t)bh2 * S_LEN * DH);

    // 4 waves stage 32KB: waves 0-1 K (8KB each), waves 2-3 V (8KB each)
    auto stage = [&](int t) {
        const char* src = ((wid >> 1) ? vsrc : ksrc) + (size_t)t * 16384 + (size_t)(wid & 1) * 8192;
        char* dst = ((wid >> 1) ? (char*)&vbuf[0] : (char*)&kbuf[0]) + (wid & 1) * 8192;
        #pragma unroll
        for (int i = 0; i < 8; ++i) gld16(src + i * 1024 + lane * 16, dst + i * 1024);
    };

    for (int pass = 0; pass < 2; ++pass) {
        const int qx = pass ? px : (NQT - 1 - px);
        const int q0 = qx * 64;
        const int qr = q0 + wid * 16;

        // Q fragments: rows qr+lr, fold scale*log2(e)
        bf16x8 qf[4];
        {
            const float* qp = Q + ((size_t)(qr + lr) * BATCH + b) * (HQ * DH) + h * DH + kb * 8;
            #pragma unroll
            for (int ks = 0; ks < 4; ++ks) {
                f4 v0 = ((const f4*)(qp + ks * 32))[0];
                f4 v1 = ((const f4*)(qp + ks * 32))[1];
                short8 tq;
                #pragma unroll
                for (int j = 0; j < 4; ++j) {
                    tq[j]     = (short)f2bf(v0[j] * QS);
                    tq[4 + j] = (short)f2bf(v1[j] * QS);
                }
                qf[ks] = __builtin_bit_cast(bf16x8, tq);
            }
        }

        float mr[4];
        f32x4 accO[8];
        f32x4 accD = (f32x4){0.f, 0.f, 0.f, 0.f};
        #pragma unroll
        for (int r = 0; r < 4; ++r) mr[r] = -3.0e38f;
        #pragma unroll
        for (int d = 0; d < 8; ++d) accO[d] = (f32x4){0.f, 0.f, 0.f, 0.f};

        const int ntiles = qx + 1;

        for (int t = 0; t < ntiles; ++t) {
            stage(t);
            __syncthreads();               // staged tile ready
            const int kv0 = t * KVB;
            if (kv0 <= qr + 15) {          // skip fully-masked tiles
                // ---- S = Q K^T
                f32x4 sf[4];
                #pragma unroll
                for (int cb = 0; cb < 4; ++cb) sf[cb] = (f32x4){0.f, 0.f, 0.f, 0.f};
                __builtin_amdgcn_s_setprio(1);
                #pragma unroll
                for (int cb = 0; cb < 4; ++cb) {
                    const int krow = cb * 16 + lr;
                    const int sw = (krow & 7) << 3;
                    #pragma unroll
                    for (int ks = 0; ks < 4; ++ks) {
                        short8 kk = *(const short8*)&kbuf[krow * DH + ((ks * 32 + kb * 8) ^ sw)];
                        sf[cb] = __builtin_amdgcn_mfma_f32_16x16x32_bf16(
                            qf[ks], __builtin_bit_cast(bf16x8, kk), sf[cb], 0, 0, 0);
                    }
                }
                __builtin_amdgcn_s_setprio(0);

                // ---- causal mask (diagonal-straddling tile only)
                if (kv0 + KVB - 1 > qr) {
                    #pragma unroll
                    for (int cb = 0; cb < 4; ++cb) {
                        const int col = kv0 + cb * 16 + lr;
                        #pragma unroll
                        for (int r = 0; r < 4; ++r)
                            if (col > qr + kb * 4 + r) sf[cb][r] = -3.0e38f;
                    }
                }

                // ---- online softmax: DPP max reduce, P -> pbuf (bf16), denom via MFMA
                float al[4];
                #pragma unroll
                for (int r = 0; r < 4; ++r) {
                    float rm = fmaxf(fmaxf(sf[0][r], sf[1][r]), fmaxf(sf[2][r], sf[3][r]));
                    rm = dpp_max16(rm);
                    const float mn = fmaxf(mr[r], rm);
                    al[r] = __builtin_amdgcn_exp2f(mr[r] - mn);
                    mr[r] = mn;
                    const int row = kb * 4 + r;
                    const int sw = (row & 7) << 3;
                    #pragma unroll
                    for (int cb = 0; cb < 4; ++cb) {
                        const unsigned short pk = f2bf(__builtin_amdgcn_exp2f(sf[cb][r] - mn));
                        pbuf[wid][row * PPW + ((cb * 16 + lr) ^ sw)] = (short)pk;
                    }
                }
                // rescale accumulators
                #pragma unroll
                for (int d = 0; d < 8; ++d) {
                    #pragma unroll
                    for (int r = 0; r < 4; ++r) accO[d][r] *= al[r];
                }
                #pragma unroll
                for (int r = 0; r < 4; ++r) accD[r] *= al[r];

                // ---- read P as A-frags (row lr, swizzled), denom + PV MFMA
                const int psw = (lr & 7) << 3;
                short8 pA[2];
                #pragma unroll
                for (int ks2 = 0; ks2 < 2; ++ks2)
                    pA[ks2] = *(const short8*)&pbuf[wid][lr * PPW + ((ks2 * 32 + kb * 8) ^ psw)];

                __builtin_amdgcn_s_setprio(1);
                accD = __builtin_amdgcn_mfma_f32_16x16x32_bf16(
                    __builtin_bit_cast(bf16x8, pA[0]), ones, accD, 0, 0, 0);
                accD = __builtin_amdgcn_mfma_f32_16x16x32_bf16(
                    __builtin_bit_cast(bf16x8, pA[1]), ones, accD, 0, 0, 0);
                #pragma unroll
                for (int db = 0; db < 8; ++db) {
                    const int d = db * 16 + lr;
                    const int sw2 = (d & 7) << 3;
                    #pragma unroll
                    for (int ks2 = 0; ks2 < 2; ++ks2) {
                        short8 vv = *(const short8*)&vbuf[d * KVB + ((ks2 * 32 + kb * 8) ^ sw2)];
                        accO[db] = __builtin_amdgcn_mfma_f32_16x16x32_bf16(
                            __builtin_bit_cast(bf16x8, pA[ks2]), __builtin_bit_cast(bf16x8, vv),
                            accO[db], 0, 0, 0);
                    }
                }
                __builtin_amdgcn_s_setprio(0);
            }
            __syncthreads();               // tile consumed before next stage overwrites
        }

        float inv[4];
        #pragma unroll
        for (int r = 0; r < 4; ++r) inv[r] = 1.0f / accD[r];
        #pragma unroll
        for (int db = 0; db < 8; ++db) {
            #pragma unroll
            for (int r = 0; r < 4; ++r) {
                const int row = qr + kb * 4 + r;
                O[((size_t)row * BATCH + b) * (HQ * DH) + h * DH + db * 16 + lr] = accO[db][r] * inv[r];
            }
        }
        // trailing __syncthreads of the loop guarantees LDS safe to restage next pass
    }
}

// ---------------- fallback (verified r2 kernel) for small ws_size ----------------
__global__ __launch_bounds__(256)
void fattn_fallback(const float* __restrict__ Q, const float* __restrict__ K,
                    const float* __restrict__ V, float* __restrict__ O)
{
    __shared__ short kbuf[KVB0 * DH];
    __shared__ short vbuf[DH * VP];
    __shared__ short pbuf[4][16 * PP];

    const int bh  = blockIdx.y;
    const int b   = bh >> 4, h = bh & 15, hkv = h >> 2;
    const int q0  = blockIdx.x * QT0;
    const int tid = threadIdx.x;
    const int wid = tid >> 6;
    const int lane = tid & 63;
    const int lr  = lane & 15;
    const int kb2 = lane >> 4;
    const int qr  = q0 + wid * 16;

    const float QS = 0.127517244f;
    bf16x8 qf[4];
    {
        const float* qp = Q + ((size_t)(qr + lr) * BATCH + b) * (HQ * DH) + h * DH + kb2 * 8;
        #pragma unroll
        for (int ks = 0; ks < 4; ++ks) {
            f4 v0 = ((const f4*)(qp + ks * 32))[0];
            f4 v1 = ((const f4*)(qp + ks * 32))[1];
            short8 tq;
            #pragma unroll
            for (int j = 0; j < 4; ++j) {
                tq[j]     = (short)f2bf(v0[j] * QS);
                tq[4 + j] = (short)f2bf(v1[j] * QS);
            }
            qf[ks] = __builtin_bit_cast(bf16x8, tq);
        }
    }

    float mr[4], ls[4];
    f32x4 accO[8];
    #pragma unroll
    for (int r = 0; r < 4; ++r) { mr[r] = -3.0e38f; ls[r] = 0.0f; }
    #pragma unroll
    for (int d = 0; d < 8; ++d) accO[d] = (f32x4){0.f, 0.f, 0.f, 0.f};

    const int sr  = tid >> 3, sc = tid & 7;
    const int vr2 = (tid >> 4) * 2, vc8 = tid & 15;
    const int ntiles = q0 / KVB0 + 2;

    for (int t = 0; t < ntiles; ++t) {
        const int kv0 = t * KVB0;
        {
            const float* kp = K + ((size_t)(kv0 + sr) * BATCH + b) * (HKV * DH) + hkv * DH + sc * 16;
            f4 a0 = ((const f4*)kp)[0];
            f4 a1 = ((const f4*)kp)[1];
            f4 a2 = ((const f4*)kp)[2];
            f4 a3 = ((const f4*)kp)[3];
            short8 s0v, s1v;
            #pragma unroll
            for (int j = 0; j < 4; ++j) {
                s0v[j] = (short)f2bf(a0[j]); s0v[4 + j] = (short)f2bf(a1[j]);
                s1v[j] = (short)f2bf(a2[j]); s1v[4 + j] = (short)f2bf(a3[j]);
            }
            const int sw = (sr & 7) << 3;
            *(short8*)&kbuf[sr * DH + ((sc * 16) ^ sw)]     = s0v;
            *(short8*)&kbuf[sr * DH + ((sc * 16 + 8) ^ sw)] = s1v;
        }
        {
            const float* vp0 = V + ((size_t)(kv0 + vr2) * BATCH + b) * (HKV * DH) + hkv * DH + vc8 * 8;
            const float* vp1 = vp0 + (size_t)BATCH * HKV * DH;
            f4 b0 = ((const f4*)vp0)[0];
            f4 b1 = ((const f4*)vp0)[1];
            f4 c0 = ((const f4*)vp1)[0];
            f4 c1 = ((const f4*)vp1)[1];
            float va[8]  = {b0[0], b0[1], b0[2], b0[3], b1[0], b1[1], b1[2], b1[3]};
            float vbv[8] = {c0[0], c0[1], c0[2], c0[3], c1[0], c1[1], c1[2], c1[3]};
            #pragma unroll
            for (int j = 0; j < 8; ++j) {
                const int d = vc8 * 8 + j;
                unsigned pk = (unsigned)f2bf(va[j]) | ((unsigned)f2bf(vbv[j]) << 16);
                const int rsw = (((vr2 >> 3) ^ ((d >> 3) & 3)) << 3) + (vr2 & 7);
                *(unsigned*)&vbuf[d * VP + rsw] = pk;
            }
        }
        __syncthreads();

        f32x4 sf[2];
        sf[0] = (f32x4){0.f, 0.f, 0.f, 0.f};
        sf[1] = (f32x4){0.f, 0.f, 0.f, 0.f};
        #pragma unroll
        for (int cb = 0; cb < 2; ++cb) {
            const int krow = cb * 16 + lr;
            const int sw = (krow & 7) << 3;
            #pragma unroll
            for (int ks = 0; ks < 4; ++ks) {
                short8 kkf = *(const short8*)&kbuf[krow * DH + ((ks * 32 + kb2 * 8) ^ sw)];
                sf[cb] = __builtin_amdgcn_mfma_f32_16x16x32_bf16(
                    qf[ks], __builtin_bit_cast(bf16x8, kkf), sf[cb], 0, 0, 0);
            }
        }
        if (kv0 + KVB0 - 1 > qr) {
            #pragma unroll
            for (int cb = 0; cb < 2; ++cb) {
                const int col = kv0 + cb * 16 + lr;
                #pragma unroll
                for (int r = 0; r < 4; ++r)
                    if (col > qr + kb2 * 4 + r) sf[cb][r] = -3.0e38f;
            }
        }
        float al[4];
        #pragma unroll
        for (int r = 0; r < 4; ++r) {
            float rm = fmaxf(sf[0][r], sf[1][r]);
            rm = fmaxf(rm, __shfl_xor(rm, 1));
            rm = fmaxf(rm, __shfl_xor(rm, 2));
            rm = fmaxf(rm, __shfl_xor(rm, 4));
            rm = fmaxf(rm, __shfl_xor(rm, 8));
            const float mn = fmaxf(mr[r], rm);
            al[r] = exp2f(mr[r] - mn);
            mr[r] = mn;
            const unsigned short pk0 = f2bf(exp2f(sf[0][r] - mn));
            const unsigned short pk1 = f2bf(exp2f(sf[1][r] - mn));
            pbuf[wid][(kb2 * 4 + r) * PP + lr]      = (short)pk0;
            pbuf[wid][(kb2 * 4 + r) * PP + 16 + lr] = (short)pk1;
            float ps = bf2f(pk0) + bf2f(pk1);
            ps += __shfl_xor(ps, 1);
            ps += __shfl_xor(ps, 2);
            ps += __shfl_xor(ps, 4);
            ps += __shfl_xor(ps, 8);
            ls[r] = ls[r] * al[r] + ps;
        }
        #pragma unroll
        for (int d = 0; d < 8; ++d) {
            #pragma unroll
            for (int r = 0; r < 4; ++r) accO[d][r] *= al[r];
        }
        const short8 pA = *(const short8*)&pbuf[wid][lr * PP + kb2 * 8];
        #pragma unroll
        for (int db = 0; db < 8; ++db) {
            const int d = db * 16 + lr;
            const int rc = ((kb2 ^ ((d >> 3) & 3)) << 3);
            short8 vv = *(const short8*)&vbuf[d * VP + rc];
            accO[db] = __builtin_amdgcn_mfma_f32_16x16x32_bf16(
                __builtin_bit_cast(bf16x8, pA), __builtin_bit_cast(bf16x8, vv), accO[db], 0, 0, 0);
        }
        __syncthreads();
    }

    #pragma unroll
    for (int r = 0; r < 4; ++r) ls[r] = 1.0f / ls[r];
    #pragma unroll
    for (int db = 0; db < 8; ++db) {
        #pragma unroll
        for (int r = 0; r < 4; ++r) {
            const int row = qr + kb2 * 4 + r;
            O[((size_t)row * BATCH + b) * (HQ * DH) + h * DH + db * 16 + lr] = accO[db][r] * ls[r];
        }
    }
}

extern "C" void kernel_launch(void* const* d_in, const int* in_sizes, int n_in,
                              void* d_out, int out_size, void* d_ws, size_t ws_size,
                              hipStream_t stream)
{
    (void)in_sizes; (void)n_in; (void)out_size;
    const float* Q = (const float*)d_in[0];
    const float* K = (const float*)d_in[1];
    const float* V = (const float*)d_in[2];
    float* O = (float*)d_out;

    const size_t kv_elems = (size_t)BATCH * HKV * S_LEN * DH;   // 2,097,152
    const size_t need = kv_elems * 2 * sizeof(short);           // 8 MB
    if (ws_size >= need) {
        short* Kb = (short*)d_ws;
        short* Vb = Kb + kv_elems;
        prep_kv<<<dim3(BATCH * HKV * (S_LEN / 64)), dim3(256), 0, stream>>>(K, V, Kb, Vb);
        dim3 grid(NQT / 2, BATCH * HQ);   // 16 x 32, causal-paired (31-px, px)
        fattn_main<<<grid, dim3(256), 0, stream>>>(Q, Kb, Vb, O);
    } else {
        dim3 grid(S_LEN / QT0, BATCH * HQ);
        fattn_fallback<<<grid, dim3(256), 0, stream>>>(Q, K, V, O);
    }
}

// Round 21
// 70.945 us; speedup vs baseline: 1.2073x; 1.2073x over previous
//
#include <hip/hip_runtime.h>
#include <cstdint>
#include <cstddef>

#define S_LEN 2048
#define BATCH 2
#define HQ    16
#define HKV   4
#define DH    128
#define KVB   64
// fallback (r2 kernel) params
#define QT0   64
#define KVB0  32
#define VP    40
#define PP    40

typedef float  f4     __attribute__((ext_vector_type(4)));
typedef float  f32x4  __attribute__((ext_vector_type(4)));
typedef float  f32x16 __attribute__((ext_vector_type(16)));
typedef short  short8 __attribute__((ext_vector_type(8)));
typedef unsigned u32x4 __attribute__((ext_vector_type(4)));
typedef __bf16 bf16x8 __attribute__((ext_vector_type(8)));

__device__ __forceinline__ unsigned short f2bf(float x) {
    unsigned u = __builtin_bit_cast(unsigned, x);
    u += 0x7fffu + ((u >> 16) & 1u);          // RNE
    return (unsigned short)(u >> 16);
}
__device__ __forceinline__ void gld16(const void* g, void* l) {
    __builtin_amdgcn_global_load_lds(
        (const __attribute__((address_space(1))) unsigned int*)g,
        (__attribute__((address_space(3))) unsigned int*)l, 16, 0, 0);
}
__device__ __forceinline__ unsigned cvtpk_bf16(float lo, float hi) {
    unsigned r;
    asm("v_cvt_pk_bf16_f32 %0, %1, %2" : "=v"(r) : "v"(lo), "v"(hi));
    return r;
}

// ---------------- fused pre-pass: K -> bf16 swizzled rows AND V -> bf16 transposed tiles
__global__ __launch_bounds__(256)
void prep_kv(const float* __restrict__ K, const float* __restrict__ V,
             short* __restrict__ Kout, short* __restrict__ Vout) {
    __shared__ short t[64][136];
    const int blk = blockIdx.x, bh = blk >> 5, tile = blk & 31, tid = threadIdx.x;
    // ---- K: rows, 8-el chunks XOR-swizzled (no LDS)
    {
        const int r  = tid >> 2;                 // 0..63 row within tile
        const int s  = tile * 64 + r;
        const int c0 = (tid & 3) * 32;
        const float* src = K + ((size_t)s * (BATCH * HKV) + bh) * DH + c0;
        short* dst = Kout + ((size_t)bh * S_LEN + s) * DH;
        const int sw = (r & 7) << 3;
        #pragma unroll
        for (int ks = 0; ks < 4; ++ks) {
            f4 a  = ((const f4*)src)[ks * 2];
            f4 b2 = ((const f4*)src)[ks * 2 + 1];
            short8 o;
            #pragma unroll
            for (int j = 0; j < 4; ++j) { o[j] = (short)f2bf(a[j]); o[4 + j] = (short)f2bf(b2[j]); }
            *(short8*)&dst[(c0 + ks * 8) ^ sw] = o;
        }
    }
    // ---- V: load into LDS (bf16), then write transposed [d][kv], swizzled
    {
        const int r  = tid >> 2;
        const int c0 = (tid & 3) * 32;
        const float* src = V + ((size_t)(tile * 64 + r) * (BATCH * HKV) + bh) * DH + c0;
        #pragma unroll
        for (int m = 0; m < 8; ++m) {
            f4 x = ((const f4*)src)[m];
            #pragma unroll
            for (int j = 0; j < 4; ++j) t[r][c0 + m * 4 + j] = (short)f2bf(x[j]);
        }
    }
    __syncthreads();
    {
        const int d   = tid >> 1;             // 0..127
        const int cc0 = (tid & 1) * 32;
        const int sw  = (d & 7) << 3;
        short* dst = Vout + (size_t)bh * (S_LEN * DH) + (size_t)tile * (64 * DH) + d * 64 + cc0;
        #pragma unroll
        for (int c8 = 0; c8 < 4; ++c8) {
            const int base = (cc0 + c8 * 8) ^ sw;
            short8 v;
            #pragma unroll
            for (int j = 0; j < 8; ++j) v[j] = t[base + j][d];
            ((short8*)dst)[c8] = v;
        }
    }
}

// ---------------- main: verified r11 kernel (8-wave in-block split-K, dbuf)
__global__ __launch_bounds__(512, 1)
void fattn_main(const float* __restrict__ Q, const short* __restrict__ Kb,
                const short* __restrict__ Vb, float* __restrict__ O)
{
    __shared__ short kb[2][2][KVB * DH];   // [half][dbuf] 4 x 16KB (rows XOR-swizzled)
    __shared__ short vb[2][2][DH * KVB];   // [half][dbuf] 4 x 16KB ([d][kv] swizzled)
    __shared__ float xbuf[8][32];          // per-wave scale/denom redistribution

    const int bh  = blockIdx.x;            // 0..31
    const int b   = bh >> 4, h = bh & 15, hkv = h >> 2;
    const int bh2 = b * HKV + hkv;
    const int qx  = 15 - (int)blockIdx.y;  // longest blocks dispatch first
    const int tid = threadIdx.x;
    const int wid = tid >> 6;              // 0..7
    const int lane = tid & 63;
    const int lq  = lane & 31;
    const int hi  = lane >> 5;
    const int half = wid >> 2;             // 0: KV tiles [0,nlo), 1: [nlo,2nlo)
    const int wq0  = qx * 128 + (wid & 3) * 32;   // this wave's 32 Q-rows
    const int nlo  = qx + 1;               // iterations (= tiles per half)

    const float QS = 0.127517244f;         // (1/sqrt(128)) * log2(e)
    bf16x8 qf[8];
    {
        const float* qp = Q + ((size_t)(wq0 + lq) * BATCH + b) * (HQ * DH) + h * DH + 8 * hi;
        #pragma unroll
        for (int dstp = 0; dstp < 8; ++dstp) {
            f4 v0 = ((const f4*)(qp + dstp * 16))[0];
            f4 v1 = ((const f4*)(qp + dstp * 16))[1];
            short8 tq;
            #pragma unroll
            for (int j = 0; j < 4; ++j) {
                tq[j]     = (short)f2bf(v0[j] * QS);
                tq[4 + j] = (short)f2bf(v1[j] * QS);
            }
            qf[dstp] = __builtin_bit_cast(bf16x8, tq);
        }
    }

    f32x16 accO[4];
    #pragma unroll
    for (int dblk = 0; dblk < 4; ++dblk)
        #pragma unroll
        for (int r = 0; r < 16; ++r) accO[dblk][r] = 0.f;
    float m = -3.0e38f, dsum = 0.f;

    const char* ksrc = (const char*)(Kb + (size_t)bh2 * S_LEN * DH);
    const char* vsrc = (const char*)(Vb + (size_t)bh2 * S_LEN * DH);

    // staging: waves 0-1 K_lo, 2-3 V_lo, 4-5 K_hi, 6-7 V_hi (8KB each)
    auto stage = [&](int i) {
        const int tile = (wid >> 2) ? (nlo + i) : i;
        const int isV  = (wid >> 1) & 1;
        const char* src = (isV ? vsrc : ksrc) + (size_t)tile * 16384 + (size_t)(wid & 1) * 8192;
        char* dst = (isV ? (char*)&vb[wid >> 2][i & 1][0] : (char*)&kb[wid >> 2][i & 1][0])
                    + (wid & 1) * 8192;
        #pragma unroll
        for (int j = 0; j < 8; ++j) gld16(src + j * 1024 + lane * 16, dst + j * 1024);
    };

    stage(0);
    __syncthreads();    // vmcnt(0) drain: iter-0 tiles staged

    for (int i = 0; i < nlo; ++i) {
        if (i + 1 < nlo) stage(i + 1);     // prefetch overlaps compute
        const int t   = half ? (nlo + i) : i;
        const int kv0 = t * 64;
        if (kv0 <= wq0 + 31) {             // skip fully-masked tiles (hi waves only)
            const short* kc = kb[half][i & 1];
            const short* vc = vb[half][i & 1];

            // ---- S^T = K . Q^T : two 32x32 tiles (kv+0..31, kv+32..63)
            f32x16 s0, s1;
            #pragma unroll
            for (int r = 0; r < 16; ++r) { s0[r] = 0.f; s1[r] = 0.f; }
            const int ksw = (lq & 7) << 3;
            const int kr0 = lq * DH, kr1 = (32 + lq) * DH;
            __builtin_amdgcn_s_setprio(1);
            #pragma unroll
            for (int dstp = 0; dstp < 8; ++dstp) {
                const int off = (dstp * 16 + 8 * hi) ^ ksw;
                short8 k0 = *(const short8*)&kc[kr0 + off];
                short8 k1 = *(const short8*)&kc[kr1 + off];
                s0 = __builtin_amdgcn_mfma_f32_32x32x16_bf16(
                    __builtin_bit_cast(bf16x8, k0), qf[dstp], s0, 0, 0, 0);
                s1 = __builtin_amdgcn_mfma_f32_32x32x16_bf16(
                    __builtin_bit_cast(bf16x8, k1), qf[dstp], s1, 0, 0, 0);
            }
            __builtin_amdgcn_s_setprio(0);

            // ---- causal mask (diagonal-straddling tiles only)
            if (kv0 + 63 > wq0) {
                const int q = wq0 + lq;
                const int kvb = kv0 + 4 * hi;
                #pragma unroll
                for (int r = 0; r < 16; ++r) {
                    const int crow = (r & 3) + 8 * (r >> 2);
                    if (kvb + crow > q)      s0[r] = -3.0e38f;
                    if (kvb + 32 + crow > q) s1[r] = -3.0e38f;
                }
            }

            // ---- in-register row max (q local; exchange with lane^32)
            float pm = fmaxf(s0[0], s1[0]);
            #pragma unroll
            for (int r = 1; r < 16; ++r) pm = fmaxf(pm, fmaxf(s0[r], s1[r]));
            pm = fmaxf(pm, __shfl_xor(pm, 32));

            // ---- defer-max (THR=8 in log2 domain)
            if (!__all(pm <= m + 8.0f)) {
                const float mn = fmaxf(m, pm);
                const float al = __builtin_amdgcn_exp2f(m - mn);
                m = mn;
                if (lane < 32) xbuf[wid][lq] = al;
                #pragma unroll
                for (int g = 0; g < 4; ++g) {
                    f4 av = *(const f4*)&xbuf[wid][g * 8 + 4 * hi];
                    #pragma unroll
                    for (int i2 = 0; i2 < 4; ++i2) {
                        #pragma unroll
                        for (int dblk = 0; dblk < 4; ++dblk)
                            accO[dblk][g * 4 + i2] *= av[i2];
                    }
                }
                dsum *= al;
            }

            // ---- P = exp2(S - m); row sum
            float rs = 0.f;
            #pragma unroll
            for (int r = 0; r < 16; ++r) { s0[r] = __builtin_amdgcn_exp2f(s0[r] - m); rs += s0[r]; }
            #pragma unroll
            for (int r = 0; r < 16; ++r) { s1[r] = __builtin_amdgcn_exp2f(s1[r] - m); rs += s1[r]; }
            rs += __shfl_xor(rs, 32);
            dsum += rs;

            // ---- pack P into A-frags (cvt_pk + shfl_xor(32) + per-half select)
            bf16x8 pf[4];
            #pragma unroll
            for (int kst = 0; kst < 4; ++kst) {
                const int bo = (kst & 1) * 8;
                float p0, p1, p2, p3, p4, p5, p6, p7;
                if (kst < 2) {
                    p0 = s0[bo + 0]; p1 = s0[bo + 1]; p2 = s0[bo + 2]; p3 = s0[bo + 3];
                    p4 = s0[bo + 4]; p5 = s0[bo + 5]; p6 = s0[bo + 6]; p7 = s0[bo + 7];
                } else {
                    p0 = s1[bo + 0]; p1 = s1[bo + 1]; p2 = s1[bo + 2]; p3 = s1[bo + 3];
                    p4 = s1[bo + 4]; p5 = s1[bo + 5]; p6 = s1[bo + 6]; p7 = s1[bo + 7];
                }
                const unsigned c0 = cvtpk_bf16(p0, p1);
                const unsigned c1 = cvtpk_bf16(p2, p3);
                const unsigned c2 = cvtpk_bf16(p4, p5);
                const unsigned c3 = cvtpk_bf16(p6, p7);
                const unsigned sc0 = (unsigned)__shfl_xor((int)c0, 32);
                const unsigned sc1 = (unsigned)__shfl_xor((int)c1, 32);
                const unsigned sc2 = (unsigned)__shfl_xor((int)c2, 32);
                const unsigned sc3 = (unsigned)__shfl_xor((int)c3, 32);
                u32x4 pw;
                pw[0] = hi ? sc2 : c0;
                pw[1] = hi ? sc3 : c1;
                pw[2] = hi ? c2  : sc0;
                pw[3] = hi ? c3  : sc1;
                pf[kst] = __builtin_bit_cast(bf16x8, pw);
            }

            // ---- O += P V
            const int vsw = (lq & 7) << 3;
            __builtin_amdgcn_s_setprio(1);
            #pragma unroll
            for (int kst = 0; kst < 4; ++kst) {
                const int voff = kst * 16 + 8 * hi;
                #pragma unroll
                for (int dblk = 0; dblk < 4; ++dblk) {
                    const int d = dblk * 32 + lq;
                    short8 vv = *(const short8*)&vc[d * KVB + (voff ^ vsw)];
                    accO[dblk] = __builtin_amdgcn_mfma_f32_32x32x16_bf16(
                        pf[kst], __builtin_bit_cast(bf16x8, vv), accO[dblk], 0, 0, 0);
                }
            }
            __builtin_amdgcn_s_setprio(0);
        }
        __syncthreads();   // vmcnt(0) drain: prefetch landed; tiles consumed
    }

    // ---- split-K merge: pair (wid, wid^4) hold the same 32 Q-rows
    if (lane < 32) xbuf[wid][lq] = m;
    __syncthreads();
    const float mo = xbuf[wid ^ 4][lq];
    const float ms = fmaxf(m, mo);
    const float aa = __builtin_amdgcn_exp2f(m - ms);
    dsum *= aa;
    __syncthreads();
    if (lane < 32) xbuf[wid][lq] = dsum;        // scaled partial denom
    __syncthreads();
    dsum += xbuf[wid ^ 4][lq];                  // merged denom (per q=lq)
    __syncthreads();
    if (lane < 32) xbuf[wid][lq] = aa;          // redistribute scale by q
    #pragma unroll
    for (int g = 0; g < 4; ++g) {
        f4 av = *(const f4*)&xbuf[wid][g * 8 + 4 * hi];
        #pragma unroll
        for (int i2 = 0; i2 < 4; ++i2) {
            #pragma unroll
            for (int dblk = 0; dblk < 4; ++dblk)
                accO[dblk][g * 4 + i2] *= av[i2];
        }
    }
    __syncthreads();                            // all K/V reads done; reuse kb as scratch
    float* mb = (float*)&kb[0][0][0];           // 64KB merge slab
    if (half) {                                 // hi waves deposit scaled accO
        float* slot = mb + (size_t)(wid & 3) * 4096;
        #pragma unroll
        for (int dblk = 0; dblk < 4; ++dblk)
            #pragma unroll
            for (int r2 = 0; r2 < 4; ++r2) {
                f4 v;
                #pragma unroll
                for (int j = 0; j < 4; ++j) v[j] = accO[dblk][r2 * 4 + j];
                *(f4*)&slot[(dblk * 4 + r2) * 256 + lane * 4] = v;   // lane-coalesced
            }
    }
    __syncthreads();
    if (!half) {                                // lo waves add, normalize, store
        float* slot = mb + (size_t)(wid & 3) * 4096;
        #pragma unroll
        for (int dblk = 0; dblk < 4; ++dblk)
            #pragma unroll
            for (int r2 = 0; r2 < 4; ++r2) {
                f4 v = *(const f4*)&slot[(dblk * 4 + r2) * 256 + lane * 4];
                #pragma unroll
                for (int j = 0; j < 4; ++j) accO[dblk][r2 * 4 + j] += v[j];
            }
        if (lane < 32) xbuf[wid][lq] = dsum;    // redistribute merged denom by q
        #pragma unroll
        for (int g = 0; g < 4; ++g) {
            f4 dv = *(const f4*)&xbuf[wid][g * 8 + 4 * hi];
            #pragma unroll
            for (int i2 = 0; i2 < 4; ++i2) {
                const float inv = 1.0f / dv[i2];
                const int row = wq0 + g * 8 + i2 + 4 * hi;
                float* op = O + ((size_t)row * BATCH + b) * (HQ * DH) + h * DH + lq;
                #pragma unroll
                for (int dblk = 0; dblk < 4; ++dblk)
                    op[dblk * 32] = accO[dblk][g * 4 + i2] * inv;
            }
        }
    }
}

// ---------------- fallback (verified r2 kernel) for small ws_size ----------------
__global__ __launch_bounds__(256)
void fattn_fallback(const float* __restrict__ Q, const float* __restrict__ K,
                    const float* __restrict__ V, float* __restrict__ O)
{
    __shared__ short kbuf[KVB0 * DH];
    __shared__ short vbuf[DH * VP];
    __shared__ short pbuf[4][16 * PP];

    const int bh  = blockIdx.y;
    const int b   = bh >> 4, h = bh & 15, hkv = h >> 2;
    const int q0  = blockIdx.x * QT0;
    const int tid = threadIdx.x;
    const int wid = tid >> 6;
    const int lane = tid & 63;
    const int lr  = lane & 15;
    const int kb2 = lane >> 4;
    const int qr  = q0 + wid * 16;

    const float QS = 0.127517244f;
    bf16x8 qf[4];
    {
        const float* qp = Q + ((size_t)(qr + lr) * BATCH + b) * (HQ * DH) + h * DH + kb2 * 8;
        #pragma unroll
        for (int ks = 0; ks < 4; ++ks) {
            f4 v0 = ((const f4*)(qp + ks * 32))[0];
            f4 v1 = ((const f4*)(qp + ks * 32))[1];
            short8 tq;
            #pragma unroll
            for (int j = 0; j < 4; ++j) {
                tq[j]     = (short)f2bf(v0[j] * QS);
                tq[4 + j] = (short)f2bf(v1[j] * QS);
            }
            qf[ks] = __builtin_bit_cast(bf16x8, tq);
        }
    }

    float mr[4], ls[4];
    f32x4 accO[8];
    #pragma unroll
    for (int r = 0; r < 4; ++r) { mr[r] = -3.0e38f; ls[r] = 0.0f; }
    #pragma unroll
    for (int d = 0; d < 8; ++d) accO[d] = (f32x4){0.f, 0.f, 0.f, 0.f};

    const int sr  = tid >> 3, sc = tid & 7;
    const int vr2 = (tid >> 4) * 2, vc8 = tid & 15;
    const int ntiles = q0 / KVB0 + 2;

    for (int t = 0; t < ntiles; ++t) {
        const int kv0 = t * KVB0;
        {
            const float* kp = K + ((size_t)(kv0 + sr) * BATCH + b) * (HKV * DH) + hkv * DH + sc * 16;
            f4 a0 = ((const f4*)kp)[0];
            f4 a1 = ((const f4*)kp)[1];
            f4 a2 = ((const f4*)kp)[2];
            f4 a3 = ((const f4*)kp)[3];
            short8 s0v, s1v;
            #pragma unroll
            for (int j = 0; j < 4; ++j) {
                s0v[j] = (short)f2bf(a0[j]); s0v[4 + j] = (short)f2bf(a1[j]);
                s1v[j] = (short)f2bf(a2[j]); s1v[4 + j] = (short)f2bf(a3[j]);
            }
            const int sw = (sr & 7) << 3;
            *(short8*)&kbuf[sr * DH + ((sc * 16) ^ sw)]     = s0v;
            *(short8*)&kbuf[sr * DH + ((sc * 16 + 8) ^ sw)] = s1v;
        }
        {
            const float* vp0 = V + ((size_t)(kv0 + vr2) * BATCH + b) * (HKV * DH) + hkv * DH + vc8 * 8;
            const float* vp1 = vp0 + (size_t)BATCH * HKV * DH;
            f4 b0 = ((const f4*)vp0)[0];
            f4 b1 = ((const f4*)vp0)[1];
            f4 c0 = ((const f4*)vp1)[0];
            f4 c1 = ((const f4*)vp1)[1];
            float va[8]  = {b0[0], b0[1], b0[2], b0[3], b1[0], b1[1], b1[2], b1[3]};
            float vbv[8] = {c0[0], c0[1], c0[2], c0[3], c1[0], c1[1], c1[2], c1[3]};
            #pragma unroll
            for (int j = 0; j < 8; ++j) {
                const int d = vc8 * 8 + j;
                unsigned pk = (unsigned)f2bf(va[j]) | ((unsigned)f2bf(vbv[j]) << 16);
                const int rsw = (((vr2 >> 3) ^ ((d >> 3) & 3)) << 3) + (vr2 & 7);
                *(unsigned*)&vbuf[d * VP + rsw] = pk;
            }
        }
        __syncthreads();

        f32x4 sf[2];
        sf[0] = (f32x4){0.f, 0.f, 0.f, 0.f};
        sf[1] = (f32x4){0.f, 0.f, 0.f, 0.f};
        #pragma unroll
        for (int cb = 0; cb < 2; ++cb) {
            const int krow = cb * 16 + lr;
            const int sw = (krow & 7) << 3;
            #pragma unroll
            for (int ks = 0; ks < 4; ++ks) {
                short8 kkf = *(const short8*)&kbuf[krow * DH + ((ks * 32 + kb2 * 8) ^ sw)];
                sf[cb] = __builtin_amdgcn_mfma_f32_16x16x32_bf16(
                    qf[ks], __builtin_bit_cast(bf16x8, kkf), sf[cb], 0, 0, 0);
            }
        }
        if (kv0 + KVB0 - 1 > qr) {
            #pragma unroll
            for (int cb = 0; cb < 2; ++cb) {
                const int col = kv0 + cb * 16 + lr;
                #pragma unroll
                for (int r = 0; r < 4; ++r)
                    if (col > qr + kb2 * 4 + r) sf[cb][r] = -3.0e38f;
            }
        }
        float al[4];
        #pragma unroll
        for (int r = 0; r < 4; ++r) {
            float rm = fmaxf(sf[0][r], sf[1][r]);
            rm = fmaxf(rm, __shfl_xor(rm, 1));
            rm = fmaxf(rm, __shfl_xor(rm, 2));
            rm = fmaxf(rm, __shfl_xor(rm, 4));
            rm = fmaxf(rm, __shfl_xor(rm, 8));
            const float mn = fmaxf(mr[r], rm);
            al[r] = exp2f(mr[r] - mn);
            mr[r] = mn;
            const unsigned short pk0 = f2bf(exp2f(sf[0][r] - mn));
            const unsigned short pk1 = f2bf(exp2f(sf[1][r] - mn));
            pbuf[wid][(kb2 * 4 + r) * PP + lr]      = (short)pk0;
            pbuf[wid][(kb2 * 4 + r) * PP + 16 + lr] = (short)pk1;
            float ps = __builtin_bit_cast(float, (unsigned)pk0 << 16)
                     + __builtin_bit_cast(float, (unsigned)pk1 << 16);
            ps += __shfl_xor(ps, 1);
            ps += __shfl_xor(ps, 2);
            ps += __shfl_xor(ps, 4);
            ps += __shfl_xor(ps, 8);
            ls[r] = ls[r] * al[r] + ps;
        }
        #pragma unroll
        for (int d = 0; d < 8; ++d) {
            #pragma unroll
            for (int r = 0; r < 4; ++r) accO[d][r] *= al[r];
        }
        const short8 pA = *(const short8*)&pbuf[wid][lr * PP + kb2 * 8];
        #pragma unroll
        for (int db = 0; db < 8; ++db) {
            const int d = db * 16 + lr;
            const int rc = ((kb2 ^ ((d >> 3) & 3)) << 3);
            short8 vv = *(const short8*)&vbuf[d * VP + rc];
            accO[db] = __builtin_amdgcn_mfma_f32_16x16x32_bf16(
                __builtin_bit_cast(bf16x8, pA), __builtin_bit_cast(bf16x8, vv), accO[db], 0, 0, 0);
        }
        __syncthreads();
    }

    #pragma unroll
    for (int r = 0; r < 4; ++r) ls[r] = 1.0f / ls[r];
    #pragma unroll
    for (int db = 0; db < 8; ++db) {
        #pragma unroll
        for (int r = 0; r < 4; ++r) {
            const int row = qr + kb2 * 4 + r;
            O[((size_t)row * BATCH + b) * (HQ * DH) + h * DH + db * 16 + lr] = accO[db][r] * ls[r];
        }
    }
}

extern "C" void kernel_launch(void* const* d_in, const int* in_sizes, int n_in,
                              void* d_out, int out_size, void* d_ws, size_t ws_size,
                              hipStream_t stream)
{
    (void)in_sizes; (void)n_in; (void)out_size;
    const float* Q = (const float*)d_in[0];
    const float* K = (const float*)d_in[1];
    const float* V = (const float*)d_in[2];
    float* O = (float*)d_out;

    const size_t kv_elems = (size_t)BATCH * HKV * S_LEN * DH;   // 2,097,152
    const size_t need = kv_elems * 2 * sizeof(short);           // 8 MB
    if (ws_size >= need) {
        short* Kb = (short*)d_ws;
        short* Vb = Kb + kv_elems;
        prep_kv<<<dim3(BATCH * HKV * (S_LEN / 64)), dim3(256), 0, stream>>>(K, V, Kb, Vb);
        dim3 grid(BATCH * HQ, 16);   // x = bh, y -> qx = 15-y (longest first)
        fattn_main<<<grid, dim3(512), 0, stream>>>(Q, Kb, Vb, O);
    } else {
        dim3 grid(S_LEN / QT0, BATCH * HQ);
        fattn_fallback<<<grid, dim3(256), 0, stream>>>(Q, K, V, O);
    }
}